// Round 2
// baseline (1358.055 us; speedup 1.0000x reference)
//
#include <hip/hip_runtime.h>
#include <hip/hip_bf16.h>

// TensorProductWithScalarComponents: out[s,w',k] = sum_{u,v} Wc[(u,v),w'] * x[s,u,k]*y[s,v]
// Wc = (1/(8m)) * Wt . Wl folded on device per launch, packed in MFMA-B fragment order.
// One GEMM per irrep block (l=0,1,2), A built on the fly (outer product), bf16 MFMA 16x16x32.

typedef short bf16x8 __attribute__((ext_vector_type(8)));
typedef float f32x4  __attribute__((ext_vector_type(4)));

// round-to-nearest-even f32 -> bf16 (finite inputs), bit-level (no __hip_bfloat162 ABI)
__device__ __forceinline__ unsigned short f2bf(float f) {
    unsigned u = __float_as_uint(f);
    u += 0x7fffu + ((u >> 16) & 1u);
    return (unsigned short)(u >> 16);
}
__device__ __forceinline__ unsigned pk2bf(float a, float b) {
    return (unsigned)f2bf(a) | ((unsigned)f2bf(b) << 16);
}

// ---------------- prologue: fold Wl into Wt, scale, pack into MFMA-B fragment layout ----------
// Packed element (kc, nt, lane, j) <-> (u = kc%M, vh = kc/M, v = vh*32 + (lane>>4)*8 + j,
//                                       w' = nt*16 + (lane&15))
// stored at Bp[((kc*NT + nt)*64 + lane)*8 + j]   (K-order: vh outer, u inner)
template<int M, int NT>
__global__ void pack_b(const float* __restrict__ Wt, const float* __restrict__ Wl,
                       __hip_bfloat16* __restrict__ Bp, float scale) {
    const int gid = blockIdx.x * 256 + threadIdx.x;
    const int total = M * 64 * M;            // (u,v) x w'
    if (gid >= total) return;
    const int w_ = gid & (M - 1);            // output channel w'
    const int uv = gid / M;
    const int u = uv >> 6, v = uv & 63;
    const float4* wt4 = (const float4*)(Wt + (size_t)uv * M);
    float acc = 0.f;
    #pragma unroll 4
    for (int w = 0; w < M; w += 4) {
        float4 t = wt4[w >> 2];
        acc += t.x * Wl[(w + 0) * M + w_] + t.y * Wl[(w + 1) * M + w_]
             + t.z * Wl[(w + 2) * M + w_] + t.w * Wl[(w + 3) * M + w_];
    }
    acc *= scale;
    const int vh = v >> 5, vv = v & 31, quad = vv >> 3, j = vv & 7;
    const int kc = vh * M + u, nt = w_ >> 4, lane = quad * 16 + (w_ & 15);
    ((unsigned short*)Bp)[((size_t)(kc * NT + nt) * 64 + lane) * 8 + j] = f2bf(acc);
}

// ---------------- main fused GEMM ----------------
template<int M, int NCOMP, int XOFF, int NT, int MT, int WAVES_N, int LOGM>
__device__ __forceinline__ void tp_block(char* smem, int wg,
    const float* __restrict__ x, const float* __restrict__ y,
    const __hip_bfloat16* __restrict__ Bp, float* __restrict__ out, int Rtot)
{
    constexpr int YS = 80;            // y LDS row stride (bf16), 16B-aligned rows
    constexpr int XS = MT + 8;        // x LDS row stride: breaks 64-way staging-write conflict
    constexpr int WAVES_M = 4 / WAVES_N;
    constexpr int WM = (MT / 16) / WAVES_M;   // m-frags per wave (=4)
    constexpr int WN = NT / WAVES_N;          // B-frags per wave

    unsigned short* xr = (unsigned short*)smem;                       // [M][XS]
    unsigned short* yl = (unsigned short*)(smem + M * XS * 2);        // [MT][YS]
    const int tid = threadIdx.x;
    const int r0 = wg * MT;

    // stage x transposed: xr[u][row] = x[s(row), XOFF + u*NCOMP + k(row)]
    for (int idx = tid; idx < M * MT; idx += 256) {
        const int u = idx & (M - 1);
        const int row = idx >> LOGM;
        const int R = r0 + row;
        float v = 0.f;
        if (R < Rtot) {
            const int s = R / NCOMP;
            const int k = R - s * NCOMP;
            v = x[(size_t)s * 480 + XOFF + u * NCOMP + k];
        }
        xr[u * XS + row] = f2bf(v);
    }
    // stage y per-row (duplicated across k-components of a sample)
    for (int idx = tid; idx < MT * 64; idx += 256) {
        const int v_ = idx & 63;
        const int row = idx >> 6;
        const int R = r0 + row;
        float val = 0.f;
        if (R < Rtot) { const int s = R / NCOMP; val = y[(size_t)s * 64 + v_]; }
        yl[row * YS + v_] = f2bf(val);
    }
    __syncthreads();

    const int lane = tid & 63;
    const int wv = tid >> 6;
    const int wni = wv % WAVES_N;
    const int wmi = wv / WAVES_N;
    const int l15 = lane & 15;
    const int quad = lane >> 4;

    int rowf[WM];
    #pragma unroll
    for (int f = 0; f < WM; ++f) rowf[f] = (wmi * WM + f) * 16 + l15;

    f32x4 acc[WM][WN];
    #pragma unroll
    for (int f = 0; f < WM; ++f)
        #pragma unroll
        for (int g = 0; g < WN; ++g) acc[f][g] = f32x4{0.f, 0.f, 0.f, 0.f};

    const unsigned short* xs16 = xr;
    const unsigned short* ys16 = yl;
    const bf16x8* bbase = (const bf16x8*)Bp;   // fragment index = (kc*NT+nt)*64+lane

    bf16x8 bcur[WN];
    unsigned short xcur[WM];
    #pragma unroll
    for (int g = 0; g < WN; ++g) bcur[g] = bbase[(0 * NT + wni * WN + g) * 64 + lane];
    #pragma unroll
    for (int f = 0; f < WM; ++f) xcur[f] = xs16[0 * XS + rowf[f]];

    float yf[WM][8];

    #pragma unroll 2
    for (int kc = 0; kc < 2 * M; ++kc) {
        const int u = kc & (M - 1);
        if (u == 0) {  // (re)load + unpack y fragments for this v-half; cached in regs for M chunks
            const int vh = kc >> LOGM;
            #pragma unroll
            for (int f = 0; f < WM; ++f) {
                const uint4 yv = *(const uint4*)(ys16 + rowf[f] * YS + vh * 32 + quad * 8);
                yf[f][0] = __uint_as_float(yv.x << 16);
                yf[f][1] = __uint_as_float(yv.x & 0xffff0000u);
                yf[f][2] = __uint_as_float(yv.y << 16);
                yf[f][3] = __uint_as_float(yv.y & 0xffff0000u);
                yf[f][4] = __uint_as_float(yv.z << 16);
                yf[f][5] = __uint_as_float(yv.z & 0xffff0000u);
                yf[f][6] = __uint_as_float(yv.w << 16);
                yf[f][7] = __uint_as_float(yv.w & 0xffff0000u);
            }
        }
        // prefetch next chunk's B fragments (global/L2) and x scalars (LDS)
        bf16x8 bnxt[WN];
        unsigned short xnxt[WM];
        if (kc + 1 < 2 * M) {
            const int kn = kc + 1, un = kn & (M - 1);
            #pragma unroll
            for (int g = 0; g < WN; ++g) bnxt[g] = bbase[(kn * NT + wni * WN + g) * 64 + lane];
            #pragma unroll
            for (int f = 0; f < WM; ++f) xnxt[f] = xs16[un * XS + rowf[f]];
        }
        // build A fragments: a[j] = x[s,u,k] * y[s, vh*32 + quad*8 + j]
        bf16x8 af[WM];
        #pragma unroll
        for (int f = 0; f < WM; ++f) {
            const float xv = __uint_as_float((unsigned)xcur[f] << 16);
            union { bf16x8 v8; unsigned d[4]; } u_;
            u_.d[0] = pk2bf(xv * yf[f][0], xv * yf[f][1]);
            u_.d[1] = pk2bf(xv * yf[f][2], xv * yf[f][3]);
            u_.d[2] = pk2bf(xv * yf[f][4], xv * yf[f][5]);
            u_.d[3] = pk2bf(xv * yf[f][6], xv * yf[f][7]);
            af[f] = u_.v8;
        }
        #pragma unroll
        for (int f = 0; f < WM; ++f)
            #pragma unroll
            for (int g = 0; g < WN; ++g)
                acc[f][g] = __builtin_amdgcn_mfma_f32_16x16x32_bf16(af[f], bcur[g], acc[f][g], 0, 0, 0);
        if (kc + 1 < 2 * M) {
            #pragma unroll
            for (int g = 0; g < WN; ++g) bcur[g] = bnxt[g];
            #pragma unroll
            for (int f = 0; f < WM; ++f) xcur[f] = xnxt[f];
        }
    }

    // epilogue: C/D layout col = lane&15, row = quad*4 + reg  (m89-verified)
    #pragma unroll
    for (int f = 0; f < WM; ++f) {
        #pragma unroll
        for (int g = 0; g < WN; ++g) {
            const int col = (wni * WN + g) * 16 + l15;   // w'
            #pragma unroll
            for (int r = 0; r < 4; ++r) {
                const int R = r0 + (wmi * WM + f) * 16 + quad * 4 + r;
                if (R < Rtot) {
                    const int s = R / NCOMP;
                    const int k = R - s * NCOMP;
                    out[(size_t)s * 480 + XOFF + col * NCOMP + k] = acc[f][g][r];
                }
            }
        }
    }
}

__global__ __launch_bounds__(256, 2)
void tp_main(const float* __restrict__ x, const float* __restrict__ y,
             const __hip_bfloat16* __restrict__ B0, const __hip_bfloat16* __restrict__ B1,
             const __hip_bfloat16* __restrict__ B2, float* __restrict__ out,
             int R0, int R1, int R2, int G0, int G1)
{
    __shared__ char smem[57856];   // max over the three block configs
    const int b = blockIdx.x;
    if (b < G0)            tp_block<128, 1,   0, 8, 128, 2, 7>(smem, b,           x, y, B0, out, R0);
    else if (b < G0 + G1)  tp_block< 64, 3, 128, 4, 128, 2, 6>(smem, b - G0,      x, y, B1, out, R1);
    else                   tp_block< 32, 5, 320, 2, 256, 1, 5>(smem, b - G0 - G1, x, y, B2, out, R2);
}

extern "C" void kernel_launch(void* const* d_in, const int* in_sizes, int n_in,
                              void* d_out, int out_size, void* d_ws, size_t ws_size,
                              hipStream_t stream) {
    const float* x   = (const float*)d_in[0];
    const float* y   = (const float*)d_in[1];
    const float* Wt0 = (const float*)d_in[2];
    const float* Wl0 = (const float*)d_in[3];
    const float* Wt1 = (const float*)d_in[4];
    const float* Wl1 = (const float*)d_in[5];
    const float* Wt2 = (const float*)d_in[6];
    const float* Wl2 = (const float*)d_in[7];
    float* out = (float*)d_out;

    const int Ns = in_sizes[0] / 480;

    __hip_bfloat16* B0 = (__hip_bfloat16*)d_ws;        // 8192x128 bf16 = 2 MiB
    __hip_bfloat16* B1 = B0 + 8192 * 128;              // 4096x64  = 512 KiB
    __hip_bfloat16* B2 = B1 + 4096 * 64;               // 2048x32  = 128 KiB

    pack_b<128, 8><<<(128 * 64 * 128 + 255) / 256, 256, 0, stream>>>(Wt0, Wl0, B0, 1.f / 1024.f);
    pack_b< 64, 4><<<( 64 * 64 *  64 + 255) / 256, 256, 0, stream>>>(Wt1, Wl1, B1, 1.f /  512.f);
    pack_b< 32, 2><<<( 32 * 64 *  32 + 255) / 256, 256, 0, stream>>>(Wt2, Wl2, B2, 1.f /  256.f);

    const int R0 = Ns, R1 = Ns * 3, R2 = Ns * 5;
    const int G0 = (R0 + 127) / 128;
    const int G1 = (R1 + 127) / 128;
    const int G2 = (R2 + 255) / 256;
    tp_main<<<G0 + G1 + G2, 256, 0, stream>>>(x, y, B0, B1, B2, out, R0, R1, R2, G0, G1);
}